// Round 2
// baseline (3951.463 us; speedup 1.0000x reference)
//
#include <hip/hip_runtime.h>

#define N_PTS 200000
#define KNBR 27
#define EPS_BN 1e-5f

typedef __attribute__((ext_vector_type(8))) short short8;
typedef __attribute__((ext_vector_type(4))) float f32x4;

// ---- workspace layout (bytes) ----
#define WS_POOL_SUM   0u        // 8*256 f32
#define WS_POOL_CNT   8192u     // 8 f32
#define WS_BR_SUM     8448u     // 4*64 f32
#define WS_BR_SQ      9472u
#define WS_C_SUM      10496u    // 256 f32
#define WS_C_SQ       11520u
#define WS_ZROW       12544u    // (unused now; kept for layout stability)
#define WS_A_BR       16384u    // 4*64 f32 BN scale
#define WS_D_BR       17408u    // 4*64 f32 BN shift
#define WS_AC         18432u    // 256 f32
#define WS_DC         19456u
#define WS_R5         20480u    // 8*64 bf16 pooled-branch table
#define WS_WT1        24576u    // 64*256 bf16
#define WS_WTC        57344u    // 256*320 bf16
#define WS_WT6        221184u   // 27*64*256 bf16
#define WS_WT12       1105920u
#define WS_WT18       1990656u
#define WS_Y          3145728u  // 4 * N*64 bf16 pre-BN branch outputs
#define Y_STRIDE      12800000u // elements per branch
// x_bf16 table (200001 rows * 256 ch * 2B = 102.4 MB) lives in d_out, which is
// dead until gemm_c overwrites it with z.

__device__ __forceinline__ float bf2f(unsigned short u) {
  union { unsigned int i; float f; } c; c.i = ((unsigned int)u) << 16; return c.f;
}
__device__ __forceinline__ unsigned short f2bf(float f) {
  union { float f; unsigned int i; } c; c.f = f;
  unsigned int u = c.i;
  u += 0x7fffu + ((u >> 16) & 1u);
  return (unsigned short)(u >> 16);
}
__device__ __forceinline__ short8 load8bf(const unsigned short* p) {
  return *(const short8*)p;
}

// ---- zero the stats region ----
__global__ __launch_bounds__(256) void init_zero(float* __restrict__ p) {
  p[blockIdx.x * 256 + threadIdx.x] = 0.f;
}

// ---- x f32 -> bf16 table (incl. zero row at index N for missing neighbors) ----
__global__ __launch_bounds__(256) void cvt_x(
    const float* __restrict__ x, unsigned short* __restrict__ xb)
{
  size_t e = ((size_t)blockIdx.x * 256 + threadIdx.x) * 8;
  const size_t lim = (size_t)N_PTS * 256;
  if (e >= lim) {
    if (e < lim + 256) {            // zero row N
      short8 z = {0, 0, 0, 0, 0, 0, 0, 0};
      *(short8*)(xb + e) = z;
    }
    return;
  }
  const float4* q4 = (const float4*)(x + e);
  float4 a = q4[0], b = q4[1];
  short8 r;
  r[0] = (short)f2bf(a.x); r[1] = (short)f2bf(a.y);
  r[2] = (short)f2bf(a.z); r[3] = (short)f2bf(a.w);
  r[4] = (short)f2bf(b.x); r[5] = (short)f2bf(b.y);
  r[6] = (short)f2bf(b.z); r[7] = (short)f2bf(b.w);
  *(short8*)(xb + e) = r;
}

// ---- convert+transpose weights: W[k][ci][co] f32 -> Wt[k][co][ci] bf16 ----
__global__ __launch_bounds__(256) void prep_weights(
    const float* __restrict__ W6, const float* __restrict__ W12,
    const float* __restrict__ W18, const float* __restrict__ W1,
    const float* __restrict__ Wc, char* __restrict__ ws)
{
  int slice = blockIdx.x;
  const float* src; unsigned short* dst; int R, C;
  if (slice < 27)      { src = W6  + slice * 16384;        dst = (unsigned short*)(ws + WS_WT6)  + slice * 16384;        R = 256; C = 64; }
  else if (slice < 54) { src = W12 + (slice - 27) * 16384; dst = (unsigned short*)(ws + WS_WT12) + (slice - 27) * 16384; R = 256; C = 64; }
  else if (slice < 81) { src = W18 + (slice - 54) * 16384; dst = (unsigned short*)(ws + WS_WT18) + (slice - 54) * 16384; R = 256; C = 64; }
  else if (slice == 81){ src = W1;  dst = (unsigned short*)(ws + WS_WT1); R = 256; C = 64; }
  else                 { src = Wc;  dst = (unsigned short*)(ws + WS_WTC); R = 320; C = 256; }
  int total = R * C;
  for (int e = threadIdx.x; e < total; e += 256) {
    int r = e / C, c = e - r * C;
    dst[c * R + r] = f2bf(src[e]);
  }
}

// ---- per-batch channel sums for global average pool ----
__global__ __launch_bounds__(256) void pool_kernel(
    const float* __restrict__ x, const int* __restrict__ bidx,
    float* __restrict__ pool_sum, float* __restrict__ pool_cnt)
{
  int c = threadIdx.x;
  int base = blockIdx.x * 256;
  int end = base + 256; if (end > N_PTS) end = N_PTS;
  float acc = 0.f, cnt = 0.f; int cur = -1;
  for (int row = base; row < end; ++row) {
    int b = bidx[row];
    if (b != cur) {
      if (cur >= 0) {
        atomicAdd(pool_sum + cur * 256 + c, acc);
        if (c == 0) atomicAdd(pool_cnt + cur, cnt);
      }
      acc = 0.f; cnt = 0.f; cur = b;
    }
    acc += x[(size_t)row * 256 + c];
    cnt += 1.f;
  }
  if (cur >= 0) {
    atomicAdd(pool_sum + cur * 256 + c, acc);
    if (c == 0) atomicAdd(pool_cnt + cur, cnt);
  }
}

// ---- branches 0..3: dense 1x1 (conv==0) + three 27-tap gather convs ----
// Wave = 32 rows x 64 out-ch. Continuous register-ring pipeline:
//   A-gather ring: 4 chunks ahead (chunk = 2 rows x 32ch x 16B/lane)
//   W ring:        2 chunks ahead
// Rings refill across k boundaries (idx prefetched 2 k ahead), so gather
// latency is hidden by in-flight loads instead of draining each k.
__global__ __launch_bounds__(256, 4) void conv_mfma(
    const unsigned short* __restrict__ xb,
    const int* __restrict__ nbr6, const int* __restrict__ nbr12,
    const int* __restrict__ nbr18, char* __restrict__ ws)
{
  const int conv = blockIdx.y;
  const int* nbr = (conv == 1) ? nbr6 : (conv == 2) ? nbr12 : (conv == 3) ? nbr18 : nullptr;
  const unsigned short* Wt = (const unsigned short*)(ws +
      (conv == 0 ? WS_WT1 : conv == 1 ? WS_WT6 : conv == 2 ? WS_WT12 : WS_WT18));
  const int kcount = conv ? KNBR : 1;
  unsigned short* yout = (unsigned short*)(ws + WS_Y) + (size_t)conv * Y_STRIDE;
  float* sum_out = (float*)(ws + WS_BR_SUM) + conv * 64;
  float* sq_out  = (float*)(ws + WS_BR_SQ)  + conv * 64;

  const int tid = threadIdx.x;
  const int wave = tid >> 6, lane = tid & 63;
  const int m = lane & 15, q = lane >> 4;
  const int base = blockIdx.x * 128 + wave * 32;
  const int qo = q * 8;                 // channel sub-offset for this lane

  f32x4 zero4 = {0.f, 0.f, 0.f, 0.f};
  f32x4 acc[2][4];
  #pragma unroll
  for (int a = 0; a < 2; ++a)
    #pragma unroll
    for (int b = 0; b < 4; ++b) acc[a][b] = zero4;

  int rows[2], rowK[2]; bool valid[2];
  #pragma unroll
  for (int ms = 0; ms < 2; ++ms) {
    rows[ms] = base + ms * 16 + m;
    valid[ms] = rows[ms] < N_PTS;
    rowK[ms] = rows[ms] * KNBR;
  }

  // idx / pointer state: k (current) and k+1
  const unsigned short* ap0[2];
  const unsigned short* ap1[2];
  #pragma unroll
  for (int ms = 0; ms < 2; ++ms) {
    int i0 = valid[ms] ? (nbr ? nbr[rowK[ms]] : rows[ms]) : N_PTS;
    int i1 = (valid[ms] && 1 < kcount) ? nbr[rowK[ms] + 1] : N_PTS;
    ap0[ms] = xb + (size_t)i0 * 256;
    ap1[ms] = xb + (size_t)i1 * 256;
  }
  const unsigned short* wk0 = Wt;
  const unsigned short* wk1 = Wt + (size_t)(kcount > 1 ? 1 : 0) * 16384;

  // rings
  short8 Ab[4][2];   // A: slot = chunk & 3   (8 chunks per k, so static per cc)
  short8 Wb[2][4];   // W: slot = chunk & 1

  // prologue: A chunks 0..3 and W chunks 0..1 of k=0
  #pragma unroll
  for (int c = 0; c < 4; ++c)
    #pragma unroll
    for (int ms = 0; ms < 2; ++ms)
      Ab[c][ms] = load8bf(ap0[ms] + c * 32 + qo);
  #pragma unroll
  for (int c = 0; c < 2; ++c)
    #pragma unroll
    for (int t = 0; t < 4; ++t)
      Wb[c][t] = load8bf(wk0 + (t * 16 + m) * 256 + c * 32 + qo);

  #pragma unroll 1
  for (int k = 0; k < kcount; ++k) {
    // prefetch idx for k+2 (consumed at rotation below — ~13 chunks of lead)
    int idxn[2];
    #pragma unroll
    for (int ms = 0; ms < 2; ++ms)
      idxn[ms] = (valid[ms] && k + 2 < kcount) ? nbr[rowK[ms] + k + 2] : N_PTS;
    const unsigned short* wk2 = (k + 2 < kcount) ? Wt + (size_t)(k + 2) * 16384 : wk1;

    #pragma unroll
    for (int cc = 0; cc < 8; ++cc) {
      // MFMA on chunk cc (consumes Ab[cc&3], Wb[cc&1])
      #pragma unroll
      for (int ms = 0; ms < 2; ++ms)
        #pragma unroll
        for (int t = 0; t < 4; ++t)
          acc[ms][t] = __builtin_amdgcn_mfma_f32_16x16x32_bf16(Ab[cc & 3][ms], Wb[cc & 1][t], acc[ms][t], 0, 0, 0);

      // refill W chunk cc+2 (crosses into k+1 for cc>=6; clamped ptr is safe)
      {
        const int tw = cc + 2;
        const unsigned short* wsrc = (tw < 8) ? wk0 : wk1;
        const int c0w = (tw & 7) * 32 + qo;
        #pragma unroll
        for (int t = 0; t < 4; ++t)
          Wb[cc & 1][t] = load8bf(wsrc + (t * 16 + m) * 256 + c0w);
      }
      // refill A chunk cc+4 (crosses into k+1 for cc>=4; idx=N -> zero row)
      {
        const int ta = cc + 4;
        const int c0a = (ta & 7) * 32 + qo;
        #pragma unroll
        for (int ms = 0; ms < 2; ++ms)
          Ab[cc & 3][ms] = load8bf(((ta < 8) ? ap0[ms] : ap1[ms]) + c0a);
      }
    }

    // rotate k-state
    #pragma unroll
    for (int ms = 0; ms < 2; ++ms) {
      ap0[ms] = ap1[ms];
      ap1[ms] = xb + (size_t)idxn[ms] * 256;
    }
    wk0 = wk1;
    wk1 = wk2;
  }

  // BN stats: per-channel sum / sumsq (invalid rows contribute exact 0)
  #pragma unroll
  for (int t = 0; t < 4; ++t) {
    float s = 0.f, s2 = 0.f;
    #pragma unroll
    for (int ms = 0; ms < 2; ++ms)
      #pragma unroll
      for (int r = 0; r < 4; ++r) { float v = acc[ms][t][r]; s += v; s2 += v * v; }
    s  += __shfl_xor(s, 16);  s  += __shfl_xor(s, 32);
    s2 += __shfl_xor(s2, 16); s2 += __shfl_xor(s2, 32);
    if (lane < 16) {
      atomicAdd(sum_out + t * 16 + lane, s);
      atomicAdd(sq_out  + t * 16 + lane, s2);
    }
  }

  // store pre-BN y (bf16); D layout: row = q*4+r, col = m
  #pragma unroll
  for (int ms = 0; ms < 2; ++ms) {
    #pragma unroll
    for (int r = 0; r < 4; ++r) {
      int row = base + ms * 16 + q * 4 + r;
      if (row < N_PTS) {
        #pragma unroll
        for (int t = 0; t < 4; ++t)
          yout[(size_t)row * 64 + t * 16 + m] = f2bf(acc[ms][t][r]);
      }
    }
  }
}

// ---- branch BN params + pooled-branch r5 table ----
__global__ __launch_bounds__(256) void finalize_branch(
    char* __restrict__ ws,
    const float* __restrict__ g1, const float* __restrict__ be1,
    const float* __restrict__ g2, const float* __restrict__ be2,
    const float* __restrict__ g3, const float* __restrict__ be3,
    const float* __restrict__ g4, const float* __restrict__ be4,
    const float* __restrict__ g5, const float* __restrict__ be5,
    const float* __restrict__ W5)
{
  __shared__ float y5s[8][64];
  __shared__ float a5s[64], d5s[64];
  const int tid = threadIdx.x;
  float* pool_sum = (float*)(ws + WS_POOL_SUM);
  float* pool_cnt = (float*)(ws + WS_POOL_CNT);
  float* br_sum = (float*)(ws + WS_BR_SUM);
  float* br_sq  = (float*)(ws + WS_BR_SQ);
  float* a_br   = (float*)(ws + WS_A_BR);
  float* d_br   = (float*)(ws + WS_D_BR);
  unsigned short* r5 = (unsigned short*)(ws + WS_R5);

  {  // branch BN: conv biases cancel inside training-mode BN
    int conv = tid >> 6, co = tid & 63;
    const float* gp[4] = {g1, g2, g3, g4};
    const float* bp[4] = {be1, be2, be3, be4};
    float mean = br_sum[tid] / (float)N_PTS;
    float var = fmaxf(br_sq[tid] / (float)N_PTS - mean * mean, 0.f);
    float a = gp[conv][co] * rsqrtf(var + EPS_BN);
    a_br[tid] = a;
    d_br[tid] = bp[conv][co] - mean * a;
  }
  {  // y5[b][co] = mean_b @ W5 (two b's per thread)
    int co = tid & 63, b0 = tid >> 6;
    for (int b = b0; b < 8; b += 4) {
      float inv = 1.f / fmaxf(pool_cnt[b], 1.f);
      float acc = 0.f;
      for (int c = 0; c < 256; ++c)
        acc += pool_sum[b * 256 + c] * inv * W5[c * 64 + co];
      y5s[b][co] = acc;
    }
  }
  __syncthreads();
  if (tid < 64) {  // count-weighted BN stats over 8 broadcast values
    int co = tid;
    float s = 0.f, s2 = 0.f;
    for (int b = 0; b < 8; ++b) {
      float cnt = pool_cnt[b], v = y5s[b][co];
      s += cnt * v; s2 += cnt * v * v;
    }
    float mean = s / (float)N_PTS;
    float var = fmaxf(s2 / (float)N_PTS - mean * mean, 0.f);
    float a = g5[co] * rsqrtf(var + EPS_BN);
    a5s[co] = a;
    d5s[co] = be5[co] - mean * a;
  }
  __syncthreads();
  for (int i = tid; i < 512; i += 256) {
    int b = i >> 6, co = i & 63;
    float v = y5s[b][co] * a5s[co] + d5s[co];
    r5[i] = f2bf(fmaxf(v, 0.f));
  }
}

// BN+relu applied to a stored pre-BN bf16 fragment — bit-identical to a
// separate normalize pass (same f32 math, same rounding).
__device__ __forceinline__ short8 bnrelu8(short8 v, float4 a0, float4 a1,
                                          float4 d0, float4 d1) {
  const float aa[8] = {a0.x, a0.y, a0.z, a0.w, a1.x, a1.y, a1.z, a1.w};
  const float dd[8] = {d0.x, d0.y, d0.z, d0.w, d1.x, d1.y, d1.z, d1.w};
  const unsigned short* u = (const unsigned short*)&v;
  short8 o;
  #pragma unroll
  for (int j = 0; j < 8; ++j)
    o[j] = (short)f2bf(fmaxf(bf2f(u[j]) * aa[j] + dd[j], 0.f));
  return o;
}

// ---- final 320->256 GEMM over concat (branch BN+relu fused into A-load),
//      stats, z (f32) -> d_out ----
__global__ __launch_bounds__(256) void gemm_c(
    char* __restrict__ ws, const int* __restrict__ batch_idx,
    float* __restrict__ z)
{
  const unsigned short* y   = (const unsigned short*)(ws + WS_Y);
  const unsigned short* r5  = (const unsigned short*)(ws + WS_R5);
  const unsigned short* WtC = (const unsigned short*)(ws + WS_WTC);
  const float* a_br = (const float*)(ws + WS_A_BR);
  const float* d_br = (const float*)(ws + WS_D_BR);
  float* c_sum = (float*)(ws + WS_C_SUM);
  float* c_sq  = (float*)(ws + WS_C_SQ);

  const int tid = threadIdx.x;
  const int wave = tid >> 6, lane = tid & 63;
  const int m = lane & 15, q = lane >> 4;
  const int row0 = blockIdx.x * 64;
  const int cob = wave * 64;

  int rows[4], bb[4];
  #pragma unroll
  for (int ms = 0; ms < 4; ++ms) {
    rows[ms] = row0 + ms * 16 + m;
    bb[ms] = batch_idx[rows[ms]];
  }

  f32x4 zero4 = {0.f, 0.f, 0.f, 0.f};
  f32x4 acc[4][4];
  #pragma unroll
  for (int a = 0; a < 4; ++a)
    #pragma unroll
    for (int b = 0; b < 4; ++b) acc[a][b] = zero4;

  #pragma unroll
  for (int cc = 0; cc < 10; ++cc) {
    const int br = cc >> 1;
    const int c0 = (cc & 1) * 32 + q * 8;
    short8 af[4], bfr[4];
    if (br < 4) {
      const float* ab = a_br + br * 64 + c0;
      const float* db = d_br + br * 64 + c0;
      float4 a0 = *(const float4*)ab, a1 = *(const float4*)(ab + 4);
      float4 d0 = *(const float4*)db, d1 = *(const float4*)(db + 4);
      #pragma unroll
      for (int ms = 0; ms < 4; ++ms) {
        short8 v = load8bf(y + (size_t)br * Y_STRIDE + (size_t)rows[ms] * 64 + c0);
        af[ms] = bnrelu8(v, a0, a1, d0, d1);
      }
    } else {
      #pragma unroll
      for (int ms = 0; ms < 4; ++ms)
        af[ms] = load8bf(r5 + bb[ms] * 64 + c0);
    }
    #pragma unroll
    for (int t = 0; t < 4; ++t)
      bfr[t] = load8bf(WtC + (size_t)(cob + t * 16 + m) * 320 + cc * 32 + q * 8);
    #pragma unroll
    for (int ms = 0; ms < 4; ++ms)
      #pragma unroll
      for (int t = 0; t < 4; ++t)
        acc[ms][t] = __builtin_amdgcn_mfma_f32_16x16x32_bf16(af[ms], bfr[t], acc[ms][t], 0, 0, 0);
  }

  #pragma unroll
  for (int t = 0; t < 4; ++t) {
    float s = 0.f, s2 = 0.f;
    #pragma unroll
    for (int ms = 0; ms < 4; ++ms)
      #pragma unroll
      for (int r = 0; r < 4; ++r) { float v = acc[ms][t][r]; s += v; s2 += v * v; }
    s  += __shfl_xor(s, 16);  s  += __shfl_xor(s, 32);
    s2 += __shfl_xor(s2, 16); s2 += __shfl_xor(s2, 32);
    if (lane < 16) {
      atomicAdd(c_sum + cob + t * 16 + lane, s);
      atomicAdd(c_sq  + cob + t * 16 + lane, s2);
    }
  }

  #pragma unroll
  for (int ms = 0; ms < 4; ++ms) {
    #pragma unroll
    for (int r = 0; r < 4; ++r) {
      int row = row0 + ms * 16 + q * 4 + r;
      #pragma unroll
      for (int t = 0; t < 4; ++t)
        z[(size_t)row * 256 + cob + t * 16 + m] = acc[ms][t][r];
    }
  }
}

__global__ __launch_bounds__(256) void finalize_c(
    char* __restrict__ ws, const float* __restrict__ gc,
    const float* __restrict__ bec)
{
  int c = threadIdx.x;
  float* c_sum = (float*)(ws + WS_C_SUM);
  float* c_sq  = (float*)(ws + WS_C_SQ);
  float* ac = (float*)(ws + WS_AC);
  float* dc = (float*)(ws + WS_DC);
  float mean = c_sum[c] / (float)N_PTS;
  float var = fmaxf(c_sq[c] / (float)N_PTS - mean * mean, 0.f);
  float a = gc[c] * rsqrtf(var + EPS_BN);
  ac[c] = a;
  dc[c] = bec[c] - mean * a;
}

// ---- out = relu(z*ac+dc) + x, in place over d_out (f32) ----
__global__ __launch_bounds__(256) void epilogue(
    char* __restrict__ ws, const float* __restrict__ x,
    float* __restrict__ out)
{
  size_t e = ((size_t)blockIdx.x * 256 + threadIdx.x) * 8;
  const int c = (int)(e & 255);
  const float* ac = (const float*)(ws + WS_AC);
  const float* dc = (const float*)(ws + WS_DC);
  float4 z0 = *(const float4*)(out + e);
  float4 z1 = *(const float4*)(out + e + 4);
  float4 x0 = *(const float4*)(x + e);
  float4 x1 = *(const float4*)(x + e + 4);
  float zz[8] = {z0.x, z0.y, z0.z, z0.w, z1.x, z1.y, z1.z, z1.w};
  float xx[8] = {x0.x, x0.y, x0.z, x0.w, x1.x, x1.y, x1.z, x1.w};
  #pragma unroll
  for (int j = 0; j < 8; ++j)
    zz[j] = fmaxf(zz[j] * ac[c + j] + dc[c + j], 0.f) + xx[j];
  float4 o0 = {zz[0], zz[1], zz[2], zz[3]};
  float4 o1 = {zz[4], zz[5], zz[6], zz[7]};
  *(float4*)(out + e) = o0;
  *(float4*)(out + e + 4) = o1;
}

extern "C" void kernel_launch(void* const* d_in, const int* in_sizes, int n_in,
                              void* d_out, int out_size, void* d_ws, size_t ws_size,
                              hipStream_t stream) {
  (void)in_sizes; (void)n_in; (void)out_size; (void)ws_size;
  const float* x    = (const float*)d_in[0];
  const int* nbr6   = (const int*)d_in[1];
  const int* nbr12  = (const int*)d_in[2];
  const int* nbr18  = (const int*)d_in[3];
  const int* bidx   = (const int*)d_in[4];
  const float* W1   = (const float*)d_in[5];
  const float* W6   = (const float*)d_in[7];
  const float* W12  = (const float*)d_in[9];
  const float* W18  = (const float*)d_in[11];
  const float* W5   = (const float*)d_in[13];
  const float* Wc   = (const float*)d_in[15];
  const float* g1   = (const float*)d_in[17];
  const float* be1  = (const float*)d_in[18];
  const float* g2   = (const float*)d_in[19];
  const float* be2  = (const float*)d_in[20];
  const float* g3   = (const float*)d_in[21];
  const float* be3  = (const float*)d_in[22];
  const float* g4   = (const float*)d_in[23];
  const float* be4  = (const float*)d_in[24];
  const float* g5   = (const float*)d_in[25];
  const float* be5  = (const float*)d_in[26];
  const float* gc   = (const float*)d_in[27];
  const float* bec  = (const float*)d_in[28];
  char* ws = (char*)d_ws;
  float* out = (float*)d_out;
  unsigned short* xb = (unsigned short*)d_out;

  init_zero<<<16, 256, 0, stream>>>((float*)ws);
  prep_weights<<<83, 256, 0, stream>>>(W6, W12, W18, W1, Wc, ws);
  cvt_x<<<25001, 256, 0, stream>>>(x, xb);
  pool_kernel<<<782, 256, 0, stream>>>(x, bidx,
      (float*)(ws + WS_POOL_SUM), (float*)(ws + WS_POOL_CNT));
  conv_mfma<<<dim3(1563, 4), 256, 0, stream>>>(xb, nbr6, nbr12, nbr18, ws);
  finalize_branch<<<1, 256, 0, stream>>>(ws,
      g1, be1, g2, be2, g3, be3, g4, be4, g5, be5, W5);
  gemm_c<<<3125, 256, 0, stream>>>(ws, bidx, out);
  finalize_c<<<1, 256, 0, stream>>>(ws, gc, bec);
  epilogue<<<25000, 256, 0, stream>>>(ws, x, out);
}

// Round 3
// 2423.843 us; speedup vs baseline: 1.6302x; 1.6302x over previous
//
#include <hip/hip_runtime.h>

#define N_PTS 200000
#define KNBR 27
#define EPS_BN 1e-5f

typedef __attribute__((ext_vector_type(8))) short short8;
typedef __attribute__((ext_vector_type(4))) float f32x4;

// ---- workspace layout (bytes) ----
#define WS_POOL_SUM   0u        // 8*256 f32
#define WS_POOL_CNT   8192u     // 8 f32
#define WS_BR_SUM     8448u     // 4*64 f32
#define WS_BR_SQ      9472u
#define WS_C_SUM      10496u    // 256 f32
#define WS_C_SQ       11520u
#define WS_ZROW       12544u    // (unused; layout stability)
#define WS_A_BR       16384u    // 4*64 f32 BN scale
#define WS_D_BR       17408u    // 4*64 f32 BN shift
#define WS_AC         18432u    // 256 f32
#define WS_DC         19456u
#define WS_R5         20480u    // 8*64 bf16 pooled-branch table
#define WS_WT1        24576u    // 64*256 bf16 (granule layout, see prep_weights)
#define WS_WTC        57344u    // 256*320 bf16 (row-major [co][ci] as before)
#define WS_WT6        221184u   // 27*64*256 bf16 (granule layout)
#define WS_WT12       1105920u
#define WS_WT18       1990656u
#define WS_Y          3145728u  // 4 * N*64 bf16 pre-BN branch outputs
#define Y_STRIDE      12800000u // elements per branch
// x_bf16 table (200001 rows * 256 ch * 2B = 102.4 MB) lives in d_out, dead
// until gemm_c overwrites it with z.

__device__ __forceinline__ float bf2f(unsigned short u) {
  union { unsigned int i; float f; } c; c.i = ((unsigned int)u) << 16; return c.f;
}
__device__ __forceinline__ unsigned short f2bf(float f) {
  union { float f; unsigned int i; } c; c.f = f;
  unsigned int u = c.i;
  u += 0x7fffu + ((u >> 16) & 1u);
  return (unsigned short)(u >> 16);
}
__device__ __forceinline__ short8 load8bf(const unsigned short* p) {
  return *(const short8*)p;
}

// ---- zero the stats region ----
__global__ __launch_bounds__(256) void init_zero(float* __restrict__ p) {
  p[blockIdx.x * 256 + threadIdx.x] = 0.f;
}

// ---- x f32 -> bf16 table (incl. zero row at index N for missing neighbors) ----
__global__ __launch_bounds__(256) void cvt_x(
    const float* __restrict__ x, unsigned short* __restrict__ xb)
{
  size_t e = ((size_t)blockIdx.x * 256 + threadIdx.x) * 8;
  const size_t lim = (size_t)N_PTS * 256;
  if (e >= lim) {
    if (e < lim + 256) {            // zero row N
      short8 z = {0, 0, 0, 0, 0, 0, 0, 0};
      *(short8*)(xb + e) = z;
    }
    return;
  }
  const float4* q4 = (const float4*)(x + e);
  float4 a = q4[0], b = q4[1];
  short8 r;
  r[0] = (short)f2bf(a.x); r[1] = (short)f2bf(a.y);
  r[2] = (short)f2bf(a.z); r[3] = (short)f2bf(a.w);
  r[4] = (short)f2bf(b.x); r[5] = (short)f2bf(b.y);
  r[6] = (short)f2bf(b.z); r[7] = (short)f2bf(b.w);
  *(short8*)(xb + e) = r;
}

// ---- convert weights to the conv_mfma LDS granule layout ----
// For 64x256 slices (W6/W12/W18 per-k, W1): element e of a slice encodes
//   g = e>>3 (16B granule), j = e&7
//   q = g&3, m = (g>>2)&15, t = (g>>6)&3, cc = g>>8
//   holds W[ci = cc*32 + q*8 + j][co = t*16 + m]
// so a block can stage the slice LINEARLY into LDS and lane(m,q) reads its
// B-fragment for (cc,t) at granule (cc*4+t)*64 + m*4 + q.
// Wc keeps the old row-major [co][ci320] layout (gemm_c unchanged).
__global__ __launch_bounds__(256) void prep_weights(
    const float* __restrict__ W6, const float* __restrict__ W12,
    const float* __restrict__ W18, const float* __restrict__ W1,
    const float* __restrict__ Wc, char* __restrict__ ws)
{
  int slice = blockIdx.x;
  if (slice < 82) {
    const float* src; unsigned short* dst;
    if (slice < 27)      { src = W6  + slice * 16384;        dst = (unsigned short*)(ws + WS_WT6)  + slice * 16384; }
    else if (slice < 54) { src = W12 + (slice - 27) * 16384; dst = (unsigned short*)(ws + WS_WT12) + (slice - 27) * 16384; }
    else if (slice < 81) { src = W18 + (slice - 54) * 16384; dst = (unsigned short*)(ws + WS_WT18) + (slice - 54) * 16384; }
    else                 { src = W1;  dst = (unsigned short*)(ws + WS_WT1); }
    for (int e = threadIdx.x; e < 16384; e += 256) {
      int g = e >> 3, j = e & 7;
      int qq = g & 3, mm = (g >> 2) & 15, t = (g >> 6) & 3, cc = g >> 8;
      int ci = cc * 32 + qq * 8 + j;
      int co = t * 16 + mm;
      dst[e] = f2bf(src[ci * 64 + co]);
    }
  } else {
    const float* src = Wc;
    unsigned short* dst = (unsigned short*)(ws + WS_WTC);
    for (int e = threadIdx.x; e < 320 * 256; e += 256) {
      int r = e >> 8, c = e & 255;               // r = ci(320), c = co(256)
      dst[c * 320 + r] = f2bf(src[e]);
    }
  }
}

// ---- per-batch channel sums for global average pool ----
__global__ __launch_bounds__(256) void pool_kernel(
    const float* __restrict__ x, const int* __restrict__ bidx,
    float* __restrict__ pool_sum, float* __restrict__ pool_cnt)
{
  int c = threadIdx.x;
  int base = blockIdx.x * 256;
  int end = base + 256; if (end > N_PTS) end = N_PTS;
  float acc = 0.f, cnt = 0.f; int cur = -1;
  for (int row = base; row < end; ++row) {
    int b = bidx[row];
    if (b != cur) {
      if (cur >= 0) {
        atomicAdd(pool_sum + cur * 256 + c, acc);
        if (c == 0) atomicAdd(pool_cnt + cur, cnt);
      }
      acc = 0.f; cnt = 0.f; cur = b;
    }
    acc += x[(size_t)row * 256 + c];
    cnt += 1.f;
  }
  if (cur >= 0) {
    atomicAdd(pool_sum + cur * 256 + c, acc);
    if (c == 0) atomicAdd(pool_cnt + cur, cnt);
  }
}

// ---- branches 0..3: dense 1x1 (conv==0) + three 27-tap gather convs ----
// Round-1 A-path (64 rows x 64 out-ch per wave, idx prefetched 1 k ahead).
// NEW: the 32 KB weight k-slice is staged into LDS once per block per k
// (coalesced 128 B/thread, XOR-swizzled for conflict-free ds_write/ds_read),
// removing the 16-way-divergent W VMEM loads from the gather queue.
// Swizzle: logical granule g <-> phys byte = g*16 ^ ((g>>3 & 7)<<4).
__global__ __launch_bounds__(256) void conv_mfma(
    const unsigned short* __restrict__ xb,
    const int* __restrict__ nbr6, const int* __restrict__ nbr12,
    const int* __restrict__ nbr18, char* __restrict__ ws)
{
  __shared__ unsigned short Wlds[16384];   // 32 KB, one k-slice

  const int conv = blockIdx.y;
  const int* nbr = (conv == 1) ? nbr6 : (conv == 2) ? nbr12 : (conv == 3) ? nbr18 : nullptr;
  const unsigned short* Wt = (const unsigned short*)(ws +
      (conv == 0 ? WS_WT1 : conv == 1 ? WS_WT6 : conv == 2 ? WS_WT12 : WS_WT18));
  const int kcount = conv ? KNBR : 1;
  unsigned short* yout = (unsigned short*)(ws + WS_Y) + (size_t)conv * Y_STRIDE;
  float* sum_out = (float*)(ws + WS_BR_SUM) + conv * 64;
  float* sq_out  = (float*)(ws + WS_BR_SQ)  + conv * 64;

  const int tid = threadIdx.x;
  const int wave = tid >> 6, lane = tid & 63;
  const int m = lane & 15, q = lane >> 4;
  const int base = blockIdx.x * 256 + wave * 64;
  const int tid7 = tid & 7;
  char* WldsB = (char*)Wlds;
  // read-side swizzled element offset for this lane (bytes/2)
  const int rvo = ((((m * 4 + q) * 16) ^ (((m >> 1) & 7) * 16)) >> 1);

  f32x4 zero4 = {0.f, 0.f, 0.f, 0.f};
  f32x4 acc[4][4];
  #pragma unroll
  for (int a = 0; a < 4; ++a)
    #pragma unroll
    for (int b = 0; b < 4; ++b) acc[a][b] = zero4;

  int rows[4]; bool valid[4];
  #pragma unroll
  for (int ms = 0; ms < 4; ++ms) {
    rows[ms] = base + ms * 16 + m;
    valid[ms] = rows[ms] < N_PTS;
  }

  // prologue: indices for k=0 (tail/missing -> N = zero row)
  int idxc[4];
  #pragma unroll
  for (int ms = 0; ms < 4; ++ms)
    idxc[ms] = valid[ms] ? (nbr ? nbr[rows[ms] * KNBR] : rows[ms]) : N_PTS;

  #pragma unroll 1
  for (int k = 0; k < kcount; ++k) {
    // prefetch next k's indices (off the critical path)
    int idxn[4];
    #pragma unroll
    for (int ms = 0; ms < 4; ++ms)
      idxn[ms] = (k + 1 < kcount && valid[ms]) ? nbr[rows[ms] * KNBR + k + 1] : N_PTS;

    // ---- stage W slice k into LDS (coalesced 128 B/thread, swizzled) ----
    __syncthreads();                       // prior k's readers done
    {
      const unsigned short* gW = Wt + (size_t)k * 16384 + tid * 64;
      short8 wreg[8];
      #pragma unroll
      for (int j = 0; j < 8; ++j) wreg[j] = load8bf(gW + j * 8);
      #pragma unroll
      for (int j = 0; j < 8; ++j)
        *(short8*)(WldsB + tid * 128 + ((j ^ tid7) << 4)) = wreg[j];
    }
    __syncthreads();                       // slice k visible

    const unsigned short* ap[4];
    #pragma unroll
    for (int ms = 0; ms < 4; ++ms) ap[ms] = xb + (size_t)idxc[ms] * 256;

    #pragma unroll
    for (int cc = 0; cc < 8; ++cc) {
      const int c0 = cc * 32 + q * 8;
      short8 af[4], bfr[4];
      #pragma unroll
      for (int ms = 0; ms < 4; ++ms) af[ms] = load8bf(ap[ms] + c0);
      #pragma unroll
      for (int t = 0; t < 4; ++t)
        bfr[t] = load8bf(Wlds + (cc * 4 + t) * 512 + rvo);
      #pragma unroll
      for (int ms = 0; ms < 4; ++ms)
        #pragma unroll
        for (int t = 0; t < 4; ++t)
          acc[ms][t] = __builtin_amdgcn_mfma_f32_16x16x32_bf16(af[ms], bfr[t], acc[ms][t], 0, 0, 0);
    }
    #pragma unroll
    for (int ms = 0; ms < 4; ++ms) idxc[ms] = idxn[ms];
  }

  // BN stats: per-channel sum / sumsq (tail rows contribute exact 0)
  #pragma unroll
  for (int t = 0; t < 4; ++t) {
    float s = 0.f, s2 = 0.f;
    #pragma unroll
    for (int ms = 0; ms < 4; ++ms)
      #pragma unroll
      for (int r = 0; r < 4; ++r) { float v = acc[ms][t][r]; s += v; s2 += v * v; }
    s  += __shfl_xor(s, 16);  s  += __shfl_xor(s, 32);
    s2 += __shfl_xor(s2, 16); s2 += __shfl_xor(s2, 32);
    if (lane < 16) {
      atomicAdd(sum_out + t * 16 + lane, s);
      atomicAdd(sq_out  + t * 16 + lane, s2);
    }
  }

  // store pre-BN y (bf16); D layout: row = q*4+r, col = m
  #pragma unroll
  for (int ms = 0; ms < 4; ++ms) {
    #pragma unroll
    for (int r = 0; r < 4; ++r) {
      int row = base + ms * 16 + q * 4 + r;
      if (row < N_PTS) {
        #pragma unroll
        for (int t = 0; t < 4; ++t)
          yout[(size_t)row * 64 + t * 16 + m] = f2bf(acc[ms][t][r]);
      }
    }
  }
}

// ---- branch BN params + pooled-branch r5 table ----
__global__ __launch_bounds__(256) void finalize_branch(
    char* __restrict__ ws,
    const float* __restrict__ g1, const float* __restrict__ be1,
    const float* __restrict__ g2, const float* __restrict__ be2,
    const float* __restrict__ g3, const float* __restrict__ be3,
    const float* __restrict__ g4, const float* __restrict__ be4,
    const float* __restrict__ g5, const float* __restrict__ be5,
    const float* __restrict__ W5)
{
  __shared__ float y5s[8][64];
  __shared__ float a5s[64], d5s[64];
  const int tid = threadIdx.x;
  float* pool_sum = (float*)(ws + WS_POOL_SUM);
  float* pool_cnt = (float*)(ws + WS_POOL_CNT);
  float* br_sum = (float*)(ws + WS_BR_SUM);
  float* br_sq  = (float*)(ws + WS_BR_SQ);
  float* a_br   = (float*)(ws + WS_A_BR);
  float* d_br   = (float*)(ws + WS_D_BR);
  unsigned short* r5 = (unsigned short*)(ws + WS_R5);

  {  // branch BN: conv biases cancel inside training-mode BN
    int conv = tid >> 6, co = tid & 63;
    const float* gp[4] = {g1, g2, g3, g4};
    const float* bp[4] = {be1, be2, be3, be4};
    float mean = br_sum[tid] / (float)N_PTS;
    float var = fmaxf(br_sq[tid] / (float)N_PTS - mean * mean, 0.f);
    float a = gp[conv][co] * rsqrtf(var + EPS_BN);
    a_br[tid] = a;
    d_br[tid] = bp[conv][co] - mean * a;
  }
  {  // y5[b][co] = mean_b @ W5 (two b's per thread)
    int co = tid & 63, b0 = tid >> 6;
    for (int b = b0; b < 8; b += 4) {
      float inv = 1.f / fmaxf(pool_cnt[b], 1.f);
      float acc = 0.f;
      for (int c = 0; c < 256; ++c)
        acc += pool_sum[b * 256 + c] * inv * W5[c * 64 + co];
      y5s[b][co] = acc;
    }
  }
  __syncthreads();
  if (tid < 64) {  // count-weighted BN stats over 8 broadcast values
    int co = tid;
    float s = 0.f, s2 = 0.f;
    for (int b = 0; b < 8; ++b) {
      float cnt = pool_cnt[b], v = y5s[b][co];
      s += cnt * v; s2 += cnt * v * v;
    }
    float mean = s / (float)N_PTS;
    float var = fmaxf(s2 / (float)N_PTS - mean * mean, 0.f);
    float a = g5[co] * rsqrtf(var + EPS_BN);
    a5s[co] = a;
    d5s[co] = be5[co] - mean * a;
  }
  __syncthreads();
  for (int i = tid; i < 512; i += 256) {
    int b = i >> 6, co = i & 63;
    float v = y5s[b][co] * a5s[co] + d5s[co];
    r5[i] = f2bf(fmaxf(v, 0.f));
  }
}

// BN+relu applied to a stored pre-BN bf16 fragment — bit-identical to a
// separate normalize pass (same f32 math, same rounding).
__device__ __forceinline__ short8 bnrelu8(short8 v, float4 a0, float4 a1,
                                          float4 d0, float4 d1) {
  const float aa[8] = {a0.x, a0.y, a0.z, a0.w, a1.x, a1.y, a1.z, a1.w};
  const float dd[8] = {d0.x, d0.y, d0.z, d0.w, d1.x, d1.y, d1.z, d1.w};
  const unsigned short* u = (const unsigned short*)&v;
  short8 o;
  #pragma unroll
  for (int j = 0; j < 8; ++j)
    o[j] = (short)f2bf(fmaxf(bf2f(u[j]) * aa[j] + dd[j], 0.f));
  return o;
}

// ---- final 320->256 GEMM over concat (branch BN+relu fused into A-load),
//      stats, z (f32) -> d_out ----
__global__ __launch_bounds__(256) void gemm_c(
    char* __restrict__ ws, const int* __restrict__ batch_idx,
    float* __restrict__ z)
{
  const unsigned short* y   = (const unsigned short*)(ws + WS_Y);
  const unsigned short* r5  = (const unsigned short*)(ws + WS_R5);
  const unsigned short* WtC = (const unsigned short*)(ws + WS_WTC);
  const float* a_br = (const float*)(ws + WS_A_BR);
  const float* d_br = (const float*)(ws + WS_D_BR);
  float* c_sum = (float*)(ws + WS_C_SUM);
  float* c_sq  = (float*)(ws + WS_C_SQ);

  const int tid = threadIdx.x;
  const int wave = tid >> 6, lane = tid & 63;
  const int m = lane & 15, q = lane >> 4;
  const int row0 = blockIdx.x * 64;
  const int cob = wave * 64;

  int rows[4], bb[4];
  #pragma unroll
  for (int ms = 0; ms < 4; ++ms) {
    rows[ms] = row0 + ms * 16 + m;
    bb[ms] = batch_idx[rows[ms]];
  }

  f32x4 zero4 = {0.f, 0.f, 0.f, 0.f};
  f32x4 acc[4][4];
  #pragma unroll
  for (int a = 0; a < 4; ++a)
    #pragma unroll
    for (int b = 0; b < 4; ++b) acc[a][b] = zero4;

  #pragma unroll
  for (int cc = 0; cc < 10; ++cc) {
    const int br = cc >> 1;
    const int c0 = (cc & 1) * 32 + q * 8;
    short8 af[4], bfr[4];
    if (br < 4) {
      const float* ab = a_br + br * 64 + c0;
      const float* db = d_br + br * 64 + c0;
      float4 a0 = *(const float4*)ab, a1 = *(const float4*)(ab + 4);
      float4 d0 = *(const float4*)db, d1 = *(const float4*)(db + 4);
      #pragma unroll
      for (int ms = 0; ms < 4; ++ms) {
        short8 v = load8bf(y + (size_t)br * Y_STRIDE + (size_t)rows[ms] * 64 + c0);
        af[ms] = bnrelu8(v, a0, a1, d0, d1);
      }
    } else {
      #pragma unroll
      for (int ms = 0; ms < 4; ++ms)
        af[ms] = load8bf(r5 + bb[ms] * 64 + c0);
    }
    #pragma unroll
    for (int t = 0; t < 4; ++t)
      bfr[t] = load8bf(WtC + (size_t)(cob + t * 16 + m) * 320 + cc * 32 + q * 8);
    #pragma unroll
    for (int ms = 0; ms < 4; ++ms)
      #pragma unroll
      for (int t = 0; t < 4; ++t)
        acc[ms][t] = __builtin_amdgcn_mfma_f32_16x16x32_bf16(af[ms], bfr[t], acc[ms][t], 0, 0, 0);
  }

  #pragma unroll
  for (int t = 0; t < 4; ++t) {
    float s = 0.f, s2 = 0.f;
    #pragma unroll
    for (int ms = 0; ms < 4; ++ms)
      #pragma unroll
      for (int r = 0; r < 4; ++r) { float v = acc[ms][t][r]; s += v; s2 += v * v; }
    s  += __shfl_xor(s, 16);  s  += __shfl_xor(s, 32);
    s2 += __shfl_xor(s2, 16); s2 += __shfl_xor(s2, 32);
    if (lane < 16) {
      atomicAdd(c_sum + cob + t * 16 + lane, s);
      atomicAdd(c_sq  + cob + t * 16 + lane, s2);
    }
  }

  #pragma unroll
  for (int ms = 0; ms < 4; ++ms) {
    #pragma unroll
    for (int r = 0; r < 4; ++r) {
      int row = row0 + ms * 16 + q * 4 + r;
      #pragma unroll
      for (int t = 0; t < 4; ++t)
        z[(size_t)row * 256 + cob + t * 16 + m] = acc[ms][t][r];
    }
  }
}

__global__ __launch_bounds__(256) void finalize_c(
    char* __restrict__ ws, const float* __restrict__ gc,
    const float* __restrict__ bec)
{
  int c = threadIdx.x;
  float* c_sum = (float*)(ws + WS_C_SUM);
  float* c_sq  = (float*)(ws + WS_C_SQ);
  float* ac = (float*)(ws + WS_AC);
  float* dc = (float*)(ws + WS_DC);
  float mean = c_sum[c] / (float)N_PTS;
  float var = fmaxf(c_sq[c] / (float)N_PTS - mean * mean, 0.f);
  float a = gc[c] * rsqrtf(var + EPS_BN);
  ac[c] = a;
  dc[c] = bec[c] - mean * a;
}

// ---- out = relu(z*ac+dc) + x, in place over d_out (f32) ----
__global__ __launch_bounds__(256) void epilogue(
    char* __restrict__ ws, const float* __restrict__ x,
    float* __restrict__ out)
{
  size_t e = ((size_t)blockIdx.x * 256 + threadIdx.x) * 8;
  const int c = (int)(e & 255);
  const float* ac = (const float*)(ws + WS_AC);
  const float* dc = (const float*)(ws + WS_DC);
  float4 z0 = *(const float4*)(out + e);
  float4 z1 = *(const float4*)(out + e + 4);
  float4 x0 = *(const float4*)(x + e);
  float4 x1 = *(const float4*)(x + e + 4);
  float zz[8] = {z0.x, z0.y, z0.z, z0.w, z1.x, z1.y, z1.z, z1.w};
  float xx[8] = {x0.x, x0.y, x0.z, x0.w, x1.x, x1.y, x1.z, x1.w};
  #pragma unroll
  for (int j = 0; j < 8; ++j)
    zz[j] = fmaxf(zz[j] * ac[c + j] + dc[c + j], 0.f) + xx[j];
  float4 o0 = {zz[0], zz[1], zz[2], zz[3]};
  float4 o1 = {zz[4], zz[5], zz[6], zz[7]};
  *(float4*)(out + e) = o0;
  *(float4*)(out + e + 4) = o1;
}

extern "C" void kernel_launch(void* const* d_in, const int* in_sizes, int n_in,
                              void* d_out, int out_size, void* d_ws, size_t ws_size,
                              hipStream_t stream) {
  (void)in_sizes; (void)n_in; (void)out_size; (void)ws_size;
  const float* x    = (const float*)d_in[0];
  const int* nbr6   = (const int*)d_in[1];
  const int* nbr12  = (const int*)d_in[2];
  const int* nbr18  = (const int*)d_in[3];
  const int* bidx   = (const int*)d_in[4];
  const float* W1   = (const float*)d_in[5];
  const float* W6   = (const float*)d_in[7];
  const float* W12  = (const float*)d_in[9];
  const float* W18  = (const float*)d_in[11];
  const float* W5   = (const float*)d_in[13];
  const float* Wc   = (const float*)d_in[15];
  const float* g1   = (const float*)d_in[17];
  const float* be1  = (const float*)d_in[18];
  const float* g2   = (const float*)d_in[19];
  const float* be2  = (const float*)d_in[20];
  const float* g3   = (const float*)d_in[21];
  const float* be3  = (const float*)d_in[22];
  const float* g4   = (const float*)d_in[23];
  const float* be4  = (const float*)d_in[24];
  const float* g5   = (const float*)d_in[25];
  const float* be5  = (const float*)d_in[26];
  const float* gc   = (const float*)d_in[27];
  const float* bec  = (const float*)d_in[28];
  char* ws = (char*)d_ws;
  float* out = (float*)d_out;
  unsigned short* xb = (unsigned short*)d_out;

  init_zero<<<16, 256, 0, stream>>>((float*)ws);
  prep_weights<<<83, 256, 0, stream>>>(W6, W12, W18, W1, Wc, ws);
  cvt_x<<<25001, 256, 0, stream>>>(x, xb);
  pool_kernel<<<782, 256, 0, stream>>>(x, bidx,
      (float*)(ws + WS_POOL_SUM), (float*)(ws + WS_POOL_CNT));
  conv_mfma<<<dim3(782, 4), 256, 0, stream>>>(xb, nbr6, nbr12, nbr18, ws);
  finalize_branch<<<1, 256, 0, stream>>>(ws,
      g1, be1, g2, be2, g3, be3, g4, be4, g5, be5, W5);
  gemm_c<<<3125, 256, 0, stream>>>(ws, bidx, out);
  finalize_c<<<1, 256, 0, stream>>>(ws, gc, bec);
  epilogue<<<25000, 256, 0, stream>>>(ws, x, out);
}